// Round 9
// baseline (94.164 us; speedup 1.0000x reference)
//
#include <hip/hip_runtime.h>

constexpr int NN = 40000;
constexpr int NE = 640000;
constexpr int NBKT = 625;      // bucket = dst >> 6, 64 nodes per bucket; 625*64 == 40000
constexpr int CBLK = 128;      // count/scatter blocks; 128*5000 == NE
constexpr int NR = 5;          // src slices of 8192 rows (2 MB bf16) -> fits one XCD L2

typedef __attribute__((ext_vector_type(8))) short short8;
typedef __attribute__((ext_vector_type(4))) float f32x4;

// f32 -> bf16 round-to-nearest-even
__device__ __forceinline__ unsigned short rneb(float f) {
    unsigned u = __float_as_uint(f);
    u = (u + 0x7FFFu + ((u >> 16) & 1u)) >> 16;
    return (unsigned short)u;
}
__device__ __forceinline__ float b2f(unsigned short s) {
    return __uint_as_float(((unsigned)s) << 16);
}

// ---------- K1: fused cvtx + cvtW + per-block bucket counts (no atomics to global) ----------
__global__ __launch_bounds__(1024) void prep_k(const float* __restrict__ x,
                                               unsigned short* __restrict__ xb,
                                               const float* __restrict__ W,
                                               unsigned short* __restrict__ Wb,
                                               const int* __restrict__ dst,
                                               int* __restrict__ gcnt2) {
    __shared__ int cnt[NBKT];
    int bid = blockIdx.x, t = threadIdx.x;
    if (bid < 1250) {                            // x: 1250*1024 == NN*32 f4-groups
        int g = bid * 1024 + t;
        float4 v = reinterpret_cast<const float4*>(x)[g];
        ushort4 o = { rneb(v.x), rneb(v.y), rneb(v.z), rneb(v.w) };
        reinterpret_cast<ushort4*>(xb)[g] = o;
    } else if (bid < 1258) {                     // W: 8*1024 == 128*256/4 f4-groups
        int g = (bid - 1250) * 1024 + t;
        float4 v = reinterpret_cast<const float4*>(W)[g];
        ushort4 o = { rneb(v.x), rneb(v.y), rneb(v.z), rneb(v.w) };
        reinterpret_cast<ushort4*>(Wb)[g] = o;
    } else {                                     // counts: 128 blocks x 5000 edges
        int cb = bid - 1258;
        if (t < NBKT) cnt[t] = 0;
        __syncthreads();
        int eb = cb * 5000;
        for (int i = t; i < 5000; i += 1024)
            atomicAdd(&cnt[dst[eb + i] >> 6], 1);
        __syncthreads();
        if (t < NBKT) gcnt2[cb * 640 + t] = cnt[t];
    }
}

// ---------- K2: sum per-block counts + exclusive scan -> bptr[626], cursor[625] ----------
__global__ __launch_bounds__(1024) void cscan_k(const int* __restrict__ gcnt2,
                                                int* __restrict__ bptr,
                                                int* __restrict__ cursor) {
    __shared__ int sc[1024];
    int t = threadIdx.x;
    int c = 0;
    if (t < NBKT)
        for (int b = 0; b < CBLK; ++b) c += gcnt2[b * 640 + t];
    sc[t] = c;
    __syncthreads();
    for (int o = 1; o < 1024; o <<= 1) {
        int u = (t >= o) ? sc[t - o] : 0;
        __syncthreads();
        sc[t] += u;
        __syncthreads();
    }
    if (t < NBKT) {
        int excl = sc[t] - c;
        bptr[t]   = excl;
        cursor[t] = excl;
    }
    if (t == 0) bptr[NBKT] = NE;
}

// ---------- K3: bucket scatter: rec {src u16 | ew f16}, dloc u8 (verified R5/R6) ----------
__global__ __launch_bounds__(1024) void cscatter_k(const int* __restrict__ dst,
                                                   const int* __restrict__ src,
                                                   const float* __restrict__ ew,
                                                   int* __restrict__ cursor,
                                                   unsigned* __restrict__ rec,
                                                   unsigned char* __restrict__ dloc) {
    __shared__ int cnt[NBKT];
    __shared__ int base[NBKT];
    int t = threadIdx.x;
    if (t < NBKT) cnt[t] = 0;
    __syncthreads();
    int eb = blockIdx.x * 5000;
    for (int i = t; i < 5000; i += 1024)
        atomicAdd(&cnt[dst[eb + i] >> 6], 1);
    __syncthreads();
    if (t < NBKT) {
        base[t] = atomicAdd(&cursor[t], cnt[t]);   // reserve contiguous run
        cnt[t]  = 0;                               // reuse as local cursor
    }
    __syncthreads();
    for (int i = t; i < 5000; i += 1024) {
        int d   = dst[eb + i];
        int bkt = d >> 6;
        int slot = atomicAdd(&cnt[bkt], 1);
        int p = base[bkt] + slot;
        unsigned short wh = __builtin_bit_cast(unsigned short, (_Float16)ew[eb + i]);
        rec[p]  = (unsigned)src[eb + i] | ((unsigned)wh << 16);
        dloc[p] = (unsigned char)(d & 63);
    }
}

// ---------- K4: fused aggregate + MFMA GEMM, one block per bucket ----------
// Phase 1: in-LDS regroup with key = node*5 + src_slice (slice = src>>13, 2MB
// of xb each). Gather walk = 5 sweeps, each confined to one slice so the
// concurrently-resident blocks of an XCD keep that slice L2-hot (attack on the
// L2-miss-path ceiling measured in R7/R8). Result -> bf16 into XOR-swizzled
// LDS. Phase 2: 64x256x128 MFMA epilogue (verified R7/R8).
__global__ __launch_bounds__(1024) void aggemm_k(const unsigned* __restrict__ rec,
                                                 const unsigned char* __restrict__ dloc,
                                                 const int* __restrict__ bptr,
                                                 const unsigned short* __restrict__ xb,
                                                 const unsigned short* __restrict__ Wb,
                                                 const float* __restrict__ bias_p,
                                                 float* __restrict__ out) {
    constexpr int CAP = 2048;
    constexpr int NK = 64 * NR;                  // 320 sub-keys
    __shared__ unsigned grec[CAP];
    __shared__ int cnt[NK];
    __shared__ int cur[NK];
    __shared__ int pL[NK + 1];
    __shared__ int wtot[NR];
    __shared__ unsigned short hbl[64 * 128];     // swizzled agg half, 16 KB
    int bkt = blockIdx.x, t = threadIdx.x;
    int beg = bptr[bkt], end = bptr[bkt + 1];
    int grp = t >> 4, fl = t & 15;               // 64 node-groups x 16 feature-lanes
    int wv = t >> 6, ln = t & 63;                // wave id / lane (for the 320-scan)
    const short8* xv = reinterpret_cast<const short8*>(xb);   // row stride 16 short8
    float acc[8] = {0.f, 0.f, 0.f, 0.f, 0.f, 0.f, 0.f, 0.f};
    float wsv = 0.f;

    for (int cb = beg; cb < end; cb += CAP) {
        int m = end - cb; if (m > CAP) m = CAP;
        if (t < NK) cnt[t] = 0;
        __syncthreads();
        unsigned r0 = 0, r1 = 0; int k0 = -1, k1 = -1;
        if (t < m) {
            r0 = rec[cb + t];
            k0 = (int)dloc[cb + t] * NR + (int)((r0 & 0xFFFFu) >> 13);
            atomicAdd(&cnt[k0], 1);
        }
        if (t + 1024 < m) {
            r1 = rec[cb + t + 1024];
            k1 = (int)dloc[cb + t + 1024] * NR + (int)((r1 & 0xFFFFu) >> 13);
            atomicAdd(&cnt[k1], 1);
        }
        __syncthreads();
        int sv = 0, sincl = 0;
        if (wv < NR) {                           // 5 waves scan 320 counters
            sv = cnt[wv * 64 + ln];
            sincl = sv;
            #pragma unroll
            for (int o = 1; o < 64; o <<= 1) {
                int u = __shfl_up(sincl, o);
                if (ln >= o) sincl += u;
            }
            if (ln == 63) wtot[wv] = sincl;
        }
        __syncthreads();
        if (wv < NR) {
            int off = 0;
            #pragma unroll
            for (int j = 0; j < NR; ++j) off += (j < wv) ? wtot[j] : 0;
            int idx = wv * 64 + ln;
            int excl = off + sincl - sv;
            pL[idx]  = excl;
            cur[idx] = excl;
        }
        if (t == 0) pL[NK] = m;
        __syncthreads();
        if (k0 >= 0) { int p = atomicAdd(&cur[k0], 1); grec[p] = r0; }
        if (k1 >= 0) { int p = atomicAdd(&cur[k1], 1); grec[p] = r1; }
        __syncthreads();
        #pragma unroll
        for (int rng = 0; rng < NR; ++rng) {     // 5 slice-confined sweeps
            int gb = pL[grp * NR + rng], ge = pL[grp * NR + rng + 1];
            for (int e = gb; e < ge; ++e) {
                unsigned q = grec[e];            // broadcast within 16-lane group
                short8 v = xv[(size_t)(q & 0xFFFF) * 16 + fl];
                float w = (float)__builtin_bit_cast(_Float16, (unsigned short)(q >> 16));
                wsv += w;
                #pragma unroll
                for (int i = 0; i < 8; ++i) acc[i] += w * b2f((unsigned short)v[i]);
            }
        }
        __syncthreads();                         // protect grec/cnt for next chunk
    }

    {   // write node grp's agg slice (bf16) into swizzled LDS
        float inv = 1.f / fmaxf(wsv, 1e-8f);
        short8 o;
        #pragma unroll
        for (int i = 0; i < 8; ++i) o[i] = (short)rneb(acc[i] * inv);
        int gs = fl ^ (grp & 7);                 // granule swizzle
        *reinterpret_cast<short8*>(&hbl[grp * 128 + gs * 8]) = o;
    }
    __syncthreads();

    // ---- phase 2: MFMA ----
    int w = t >> 6, l = t & 63;
    int l15 = l & 15, lg = l >> 4;
    int rt = w & 3, ct0 = w >> 2;                // wave -> row-tile, col-tiles {ct0, ct0+4}
    f32x4 acc2[2] = { (f32x4)0.f, (f32x4)0.f };
    float bias2[2] = { bias_p[ct0 * 16 + l15], bias_p[(ct0 + 4) * 16 + l15] };
    int arow = bkt * 64 + rt * 16 + l15;

    #pragma unroll
    for (int step = 0; step < 8; ++step) {
        short8 a;
        if (step < 4) {
            a = *reinterpret_cast<const short8*>(xb + (size_t)arow * 128 + step * 32 + lg * 8);
        } else {
            int r = rt * 16 + l15;
            int g = (step - 4) * 4 + lg;         // granule 0..15 in agg half
            a = *reinterpret_cast<const short8*>(&hbl[r * 128 + (g ^ (r & 7)) * 8]);
        }
        #pragma unroll
        for (int q = 0; q < 2; ++q) {
            int ct = ct0 + q * 4;
            short8 bf = *reinterpret_cast<const short8*>(Wb + (size_t)(ct * 16 + l15) * 256 + step * 32 + lg * 8);
            acc2[q] = __builtin_amdgcn_mfma_f32_16x16x32_bf16(a, bf, acc2[q], 0, 0, 0);
        }
    }

    #pragma unroll
    for (int q = 0; q < 2; ++q)
        #pragma unroll
        for (int r4 = 0; r4 < 4; ++r4) {
            int row = bkt * 64 + rt * 16 + lg * 4 + r4;
            out[(size_t)row * 128 + (ct0 + q * 4) * 16 + l15] = acc2[q][r4] + bias2[q];
        }
}

// ==================== fallback path (small ws): atomic scatter + f32 GEMM ====================

__global__ void wsum_k(const int* __restrict__ dst, const float* __restrict__ ew,
                       float* __restrict__ wsum) {
    int e = blockIdx.x * 256 + threadIdx.x;
    if (e < NE) atomicAdd(&wsum[dst[e]], ew[e]);
}

__global__ void zerof_k(float* __restrict__ p, int n4) {
    int g = blockIdx.x * 256 + threadIdx.x;
    if (g < n4) reinterpret_cast<float4*>(p)[g] = make_float4(0.f, 0.f, 0.f, 0.f);
}

__global__ void scatter_k(const int* __restrict__ src, const int* __restrict__ dst,
                          const float* __restrict__ ew, const float* __restrict__ wsum,
                          const float* __restrict__ x, float* __restrict__ agg) {
    int tid = blockIdx.x * 256 + threadIdx.x;
    int e = tid >> 5;
    int p = tid & 31;
    if (e >= NE) return;
    int s = src[e], dn = dst[e];
    float wn = ew[e] / fmaxf(wsum[dn], 1e-8f);
    float4 v = *reinterpret_cast<const float4*>(x + (size_t)s * 128 + p * 4);
    float* o = agg + (size_t)dn * 128 + p * 4;
    atomicAdd(o + 0, wn * v.x);
    atomicAdd(o + 1, wn * v.y);
    atomicAdd(o + 2, wn * v.z);
    atomicAdd(o + 3, wn * v.w);
}

__global__ __launch_bounds__(256) void gemm_f32_k(const float* __restrict__ x,
                                                  const float* __restrict__ agg,
                                                  const float* __restrict__ W,
                                                  const float* __restrict__ b,
                                                  float* __restrict__ out) {
    __shared__ float4 Wl[128 * 64];
    __shared__ float4 hl[16 * 64];
    int t = threadIdx.x;
    int base = blockIdx.x * 80;
    const float4* Wg = reinterpret_cast<const float4*>(W);
    #pragma unroll
    for (int i = 0; i < 32; ++i) {
        int f = t + i * 256;
        int r = f >> 6, kk = f & 63;
        Wl[r * 64 + (kk ^ (r & 7))] = Wg[f];
    }
    int jj = t & 63, wsl = t >> 6, sw = jj & 7;
    float bv[2] = { b[jj], b[jj + 64] };
    const float4* xg = reinterpret_cast<const float4*>(x);
    const float4* ag = reinterpret_cast<const float4*>(agg);
    for (int g = 0; g < 5; ++g) {
        int nbase = base + g * 16;
        __syncthreads();
        #pragma unroll
        for (int i = 0; i < 4; ++i) {
            int f = t + i * 256;
            int ln = f >> 6, kk = f & 63;
            size_t node = (size_t)(nbase + ln);
            hl[ln * 64 + kk] = (kk < 32) ? xg[node * 32 + kk] : ag[node * 32 + (kk - 32)];
        }
        __syncthreads();
        float acc[2][4];
        #pragma unroll
        for (int q = 0; q < 2; ++q)
            #pragma unroll
            for (int n = 0; n < 4; ++n) acc[q][n] = 0.f;
        #pragma unroll 4
        for (int kk = 0; kk < 64; ++kk) {
            float4 h[4];
            #pragma unroll
            for (int n = 0; n < 4; ++n) h[n] = hl[(wsl + 4 * n) * 64 + kk];
            #pragma unroll
            for (int q = 0; q < 2; ++q) {
                float4 wvv = Wl[(jj + q * 64) * 64 + (kk ^ sw)];
                #pragma unroll
                for (int n = 0; n < 4; ++n)
                    acc[q][n] += wvv.x * h[n].x + wvv.y * h[n].y + wvv.z * h[n].z + wvv.w * h[n].w;
            }
        }
        #pragma unroll
        for (int q = 0; q < 2; ++q)
            #pragma unroll
            for (int n = 0; n < 4; ++n)
                out[(size_t)(nbase + wsl + 4 * n) * 128 + jj + q * 64] = acc[q][n] + bv[q];
    }
}

extern "C" void kernel_launch(void* const* d_in, const int* in_sizes, int n_in,
                              void* d_out, int out_size, void* d_ws, size_t ws_size,
                              hipStream_t stream) {
    const float* x  = (const float*)d_in[0];
    const int*   ei = (const int*)d_in[1];
    const float* ew = (const float*)d_in[2];
    const float* W  = (const float*)d_in[3];
    const float* b  = (const float*)d_in[4];
    float* out = (float*)d_out;
    const int* src = ei;
    const int* dst = ei + NE;

    // ws layout (bytes):
    //   0        : bptr [626 int]
    //   4096     : cursor [625 int]
    //   8192     : gcnt2 [128][640] int (327680) -> ends 335872
    //   339968   : Wb [128x256 bf16] (64 KB) -> ends 405504
    //   405504   : dloc [640000 u8] -> ends 1045504
    //   1048576  : rec [640000 u32] (2.56 MB) -> ends 3608576
    //   3670016  : xb [40000][128] bf16 (10.24 MB) -> need ~13.9 MB
    const size_t off_cursor = 4096;
    const size_t off_gcnt2  = 8192;
    const size_t off_Wb     = 339968;
    const size_t off_dloc   = 405504;
    const size_t off_rec    = 1048576;
    const size_t off_xb     = 3670016;
    const size_t need = off_xb + (size_t)NN * 128 * 2;

    if (ws_size >= need) {
        int* bptr   = (int*)d_ws;
        int* cursor = (int*)((char*)d_ws + off_cursor);
        int* gcnt2  = (int*)((char*)d_ws + off_gcnt2);
        unsigned short* Wb = (unsigned short*)((char*)d_ws + off_Wb);
        unsigned char* dloc = (unsigned char*)((char*)d_ws + off_dloc);
        unsigned* rec = (unsigned*)((char*)d_ws + off_rec);
        unsigned short* xb = (unsigned short*)((char*)d_ws + off_xb);

        prep_k    <<<1386, 1024, 0, stream>>>(x, xb, W, Wb, dst, gcnt2);
        cscan_k   <<<1, 1024, 0, stream>>>(gcnt2, bptr, cursor);
        cscatter_k<<<CBLK, 1024, 0, stream>>>(dst, src, ew, cursor, rec, dloc);
        aggemm_k  <<<NBKT, 1024, 0, stream>>>(rec, dloc, bptr, xb, Wb, b, out);
    } else {
        float* wsum = (float*)d_ws;
        float* agg  = out;
        zerof_k  <<<(NN / 4 + 255) / 256, 256, 0, stream>>>(wsum, NN / 4);
        zerof_k  <<<(NN * 32 + 255) / 256, 256, 0, stream>>>(agg, NN * 32);
        wsum_k   <<<(NE + 255) / 256, 256, 0, stream>>>(dst, ew, wsum);
        scatter_k<<<NE * 32 / 256, 256, 0, stream>>>(src, dst, ew, wsum, x, agg);
        gemm_f32_k<<<500, 256, 0, stream>>>(x, agg, W, b, out);
    }
}